// Round 3
// baseline (267.985 us; speedup 1.0000x reference)
//
#include <hip/hip_runtime.h>
#include <math.h>

// Problem geometry (fixed by the reference): B=32, C=16, H=W=256.
#define HW 65536
#define HW4 16384          // float4 groups per channel-plane
#define CTOT 16
#define BATCH 32
#define NPIX (BATCH * HW)  // 2,097,152 pixels per channel
#define NGRP (NPIX / 4)    // 524,288 float4 groups per channel

// Proven best (R7): 2048 task-specialized blocks sweeping contiguous spans,
// ALL global reads NON-TEMPORAL (no L3 allocate on miss -> no forced
// eviction/writeback of the harness poison-fill's dirty Infinity-Cache
// lines during our window; this was the 107 -> <77 us win).
// R8's fused finalize REGRESSED 2x (per-block __threadfence = buffer_wbl2
// x 2048 serializing at TCC).
// R9: dropped hipMemsetAsync (dedicated per-block slot, plain store) but
// finalize used runtime-indexed double w[22] -> scratch serial RMWs, +30us
// (rule #20).
// R10: static-indexed finalize (width-16 segmented shuffle) -> 263.1 us.
// R11 (this round): fuse finalize into loss_kernel WITHOUT any cache
// maintenance: per-block partials published via device-scope atomicExch
// (atomics execute at the coherence point -> no wbl2 needed), drained with
// s_waitcnt vmcnt(0), then an arrival counter (module __device__ global,
// NOT in poisoned ws) atomicAdd. Last arriver re-reads slots via
// coherence-point reads (atomicAdd(p,0)) and runs the identical reduce +
// formula, then resets the counter. Saves the finalize dispatch + gap.
#define GRID_BLOCKS 2048

__device__ unsigned int g_counter = 0;   // module .data: zero-init, self-resetting

typedef float f32x4 __attribute__((ext_vector_type(4)));

__device__ __forceinline__ float4 ldnt(const float4* p) {
    f32x4 v = __builtin_nontemporal_load((const f32x4*)p);
    float4 r; r.x = v.x; r.y = v.y; r.z = v.z; r.w = v.w;
    return r;
}

__device__ __forceinline__ float smooth_l1(float p, float g) {
    float d = fabsf(p - g);
    return (d < 1.0f) ? 0.5f * d * d : d - 0.5f;
}
// a=|x| >= 0 so 1+exp(-a) in (1,2]: plain __logf is safe (abs err < 6e-8).
__device__ __forceinline__ float bce_logits(float x, float t) {
    float e = __expf(-fabsf(x));
    return fmaxf(x, 0.0f) - x * t + __logf(1.0f + e);
}
__device__ __forceinline__ float sigmoid_fast(float x) {
    return __builtin_amdgcn_rcpf(1.0f + __expf(-x));
}
__device__ __forceinline__ float get4(const float4& v, int j) {
    return j == 0 ? v.x : (j == 1 ? v.y : (j == 2 ? v.z : v.w));
}

__global__ __launch_bounds__(256) void loss_kernel(const float* __restrict__ preds,
                                                   const float* __restrict__ gts,
                                                   unsigned long long* __restrict__ ws,
                                                   float* __restrict__ out) {
    const float4* pf = (const float4*)preds;
    const float4* gf = (const float4*)gts;
    const int blk = blockIdx.x;
    const int tid = threadIdx.x;

    float acc0 = 0.0f, acc1 = 0.0f, acc2 = 0.0f;

    if (blk < 512) {
        // ---------------- BCE task: 2 dense streams ----------------
        const int task = blk >> 7;                    // 0..3
        const int chs[4]   = {15, 14, 0, 7};
        const int ch = chs[task];
        const int lblk = blk & 127;
        const int start = lblk << 12;                 // span 4096 groups
        const int b = start >> 14;
        const int hw4s = start & (HW4 - 1);
        const size_t off = ((size_t)b * CTOT + ch) * HW4 + hw4s;
        const float4* pp = pf + off;
        const float4* gp = gf + off;
#pragma unroll 4
        for (int i = 0; i < 16; ++i) {
            const int o = (i << 8) + tid;
            float4 p = ldnt(pp + o);
            float4 t = ldnt(gp + o);
#pragma unroll
            for (int j = 0; j < 4; ++j) {
                float x  = get4(p, j);
                float tv = get4(t, j);
                float loss = bce_logits(x, tv);
                float pos  = (tv != 0.0f) ? 1.0f : 0.0f;
                acc0 += loss * pos;
                acc1 += loss * (1.0f - pos);
                acc2 += pos;
            }
        }
    } else if (blk < 1536) {
        // ---------------- displacement task: 8 dense streams ----------------
        const int task = (blk - 512) >> 9;            // 0..1
        const int c0 = task == 0 ? 1 : 8;
        const int lblk = (blk - 512) & 511;
        const int start = lblk << 10;                 // span 1024 groups
        const int b = start >> 14;
        const int hw4s = start & (HW4 - 1);
        const size_t off = ((size_t)b * CTOT + c0) * HW4 + hw4s;
        const float4* pp = pf + off;
        const float4* gp = gf + off;
#pragma unroll 2
        for (int i = 0; i < 4; ++i) {
            const int o = (i << 8) + tid;
            float4 p0 = ldnt(pp + o + 0 * HW4);
            float4 p1 = ldnt(pp + o + 1 * HW4);
            float4 p2 = ldnt(pp + o + 2 * HW4);
            float4 p3 = ldnt(pp + o + 3 * HW4);
            float4 g0 = ldnt(gp + o + 0 * HW4);
            float4 g1 = ldnt(gp + o + 1 * HW4);
            float4 g2 = ldnt(gp + o + 2 * HW4);
            float4 g3 = ldnt(gp + o + 3 * HW4);
#pragma unroll
            for (int j = 0; j < 4; ++j) {
                float a0 = get4(p0, j), a1 = get4(p1, j), a2 = get4(p2, j), a3 = get4(p3, j);
                float b0 = get4(g0, j), b1 = get4(g1, j), b2 = get4(g2, j), b3 = get4(g3, j);
                float posv = fabsf(b0) + fabsf(b1) + fabsf(b2) + fabsf(b3);
                float m = (posv != 0.0f) ? 1.0f : 0.0f;
                float l1 = smooth_l1(a0, b0) + smooth_l1(a1, b1) +
                           smooth_l1(a2, b2) + smooth_l1(a3, b3);
                // swap = concat(pred[2:], pred[:2]) -> [p2,p3,p0,p1] vs gt
                float l2 = smooth_l1(a2, b0) + smooth_l1(a3, b1) +
                           smooth_l1(a0, b2) + smooth_l1(a1, b3);
                acc0 += fminf(l1, l2) * m;
                acc1 += m;
            }
        }
    } else {
        // ---------------- len/angle task: 4 dense streams ----------------
        const int task = (blk - 1536) >> 8;           // 0..1
        const int cl = task == 0 ? 5 : 12;
        const int lblk = (blk - 1536) & 255;
        const int start = lblk << 11;                 // span 2048 groups
        const int b = start >> 14;
        const int hw4s = start & (HW4 - 1);
        const size_t off = ((size_t)b * CTOT + cl) * HW4 + hw4s;
        const float4* pp = pf + off;
        const float4* gp = gf + off;
#pragma unroll 2
        for (int i = 0; i < 8; ++i) {
            const int o = (i << 8) + tid;
            float4 pl = ldnt(pp + o + 0 * HW4);
            float4 pa = ldnt(pp + o + 1 * HW4);
            float4 gl = ldnt(gp + o + 0 * HW4);
            float4 ga = ldnt(gp + o + 1 * HW4);
#pragma unroll
            for (int j = 0; j < 4; ++j) {
                float glv = get4(gl, j);
                float m = (glv != 0.0f) ? 1.0f : 0.0f;
                acc0 += smooth_l1(sigmoid_fast(get4(pl, j)), glv) * m;
                acc1 += smooth_l1(sigmoid_fast(get4(pa, j)), get4(ga, j)) * m;
                acc2 += m;
            }
        }
    }

    // ---- wave (64-lane) butterfly reduce the (up to) 3 accumulators ----
#pragma unroll
    for (int off = 32; off > 0; off >>= 1) {
        acc0 += __shfl_down(acc0, off, 64);
        acc1 += __shfl_down(acc1, off, 64);
        acc2 += __shfl_down(acc2, off, 64);
    }

    __shared__ float red[4][3];
    __shared__ unsigned int s_old;
    const int lane = threadIdx.x & 63;
    const int wid  = threadIdx.x >> 6;
    if (lane == 0) { red[wid][0] = acc0; red[wid][1] = acc1; red[wid][2] = acc2; }
    __syncthreads();

    if (tid == 0) {
        float s0 = red[0][0] + red[1][0] + red[2][0] + red[3][0];
        float s1 = red[0][1] + red[1][1] + red[2][1] + red[3][1];
        float s2 = red[0][2] + red[1][2] + red[2][2] + red[3][2];
        // Publish the 16B partial via device-scope atomics: these execute at
        // the coherence point (no dirty L2 line, no wbl2 ever needed).
        float2 f01 = make_float2(s0, s1);
        float2 f23 = make_float2(s2, 0.0f);
        unsigned long long u01, u23;
        __builtin_memcpy(&u01, &f01, 8);
        __builtin_memcpy(&u23, &f23, 8);
        atomicExch(&ws[2 * blk + 0], u01);
        atomicExch(&ws[2 * blk + 1], u23);
        // Drain: value-atomics complete at coherence point BEFORE the
        // arrival-counter atomic issues -> publication ordering is airtight.
        asm volatile("s_waitcnt vmcnt(0)" ::: "memory");
        s_old = atomicAdd(&g_counter, 1u);
    }
    __syncthreads();

    if (s_old != GRID_BLOCKS - 1) return;   // 2047 blocks exit; last one finalizes

    // ---------------- inline finalize (last-arriver block) ----------------
    // Thread t owns slots [8t, 8t+8). Every task-region boundary (128, 256,
    // 384, 512, 1024, 1536, 1792 blocks) is a multiple of 128 blocks = 16
    // threads, so each width-16 shuffle segment maps to exactly ONE region
    // slice (static mapping; no runtime-indexed array -> no scratch):
    //   seg 0-3: the four BCE losses; seg 4-7: sol_disp; seg 8-11: tp_disp;
    //   seg 12-13: sol len/angle; seg 14-15: tp len/angle.
    {
        const int blk0 = tid << 3;
        double s0 = 0.0, s1 = 0.0, s2 = 0.0;
#pragma unroll
        for (int k = 0; k < 8; ++k) {
            // Coherence-point reads (atomic no-op RMW): sees every block's
            // published partial regardless of XCD.
            unsigned long long a = atomicAdd(&ws[2 * (blk0 + k) + 0], 0ULL);
            unsigned long long b = atomicAdd(&ws[2 * (blk0 + k) + 1], 0ULL);
            float2 f01, f23;
            __builtin_memcpy(&f01, &a, 8);
            __builtin_memcpy(&f23, &b, 8);
            s0 += (double)f01.x; s1 += (double)f01.y; s2 += (double)f23.x;
        }

        // width-16 segmented butterfly reduce
#pragma unroll
        for (int off = 8; off > 0; off >>= 1) {
            s0 += __shfl_down(s0, off, 16);
            s1 += __shfl_down(s1, off, 16);
            s2 += __shfl_down(s2, off, 16);
        }

        __shared__ double sm0[16], sm1[16], sm2[16];
        if ((tid & 15) == 0) {
            const int k = tid >> 4;
            sm0[k] = s0; sm1[k] = s1; sm2[k] = s2;
        }
        __syncthreads();

        if (tid == 0) {
            const double N = (double)NPIX;
            double line_seg   = sm0[0] / sm2[0] +  1.0 * (sm1[0] / (N - sm2[0]));
            double junc_seg   = sm0[1] / sm2[1] + 30.0 * (sm1[1] / (N - sm2[1]));
            double sol_center = sm0[2] / sm2[2] + 30.0 * (sm1[2] / (N - sm2[2]));
            double tp_center  = sm0[3] / sm2[3] + 30.0 * (sm1[3] / (N - sm2[3]));

            double sol_disp = (sm0[4] + sm0[5] + sm0[6] + sm0[7]) /
                              (sm1[4] + sm1[5] + sm1[6] + sm1[7]);
            double tp_disp  = (sm0[8] + sm0[9] + sm0[10] + sm0[11]) /
                              (sm1[8] + sm1[9] + sm1[10] + sm1[11]);

            double sl_d = sm2[12] + sm2[13];
            double sol_len   = (sm0[12] + sm0[13]) / sl_d;
            double sol_angle = (sm1[12] + sm1[13]) / sl_d;
            double tl_d = sm2[14] + sm2[15];
            double tp_len    = (sm0[14] + sm0[15]) / tl_d;
            double tp_angle  = (sm1[14] + sm1[15]) / tl_d;

            double total = 10.0 * tp_center + tp_disp + tp_len + tp_angle +
                           sol_center + sol_disp + sol_len + sol_angle +
                           line_seg + junc_seg;
            out[0] = (float)total;
            // Reset for the next graph replay (no racers left: old==2047
            // means every block already incremented).
            atomicExch(&g_counter, 0u);
        }
    }
}

extern "C" void kernel_launch(void* const* d_in, const int* in_sizes, int n_in,
                              void* d_out, int out_size, void* d_ws, size_t ws_size,
                              hipStream_t stream) {
    const float* preds = (const float*)d_in[0];
    const float* gts   = (const float*)d_in[1];
    unsigned long long* ws = (unsigned long long*)d_ws;

    loss_kernel<<<GRID_BLOCKS, 256, 0, stream>>>(preds, gts, ws, (float*)d_out);
}

// Round 4
// 256.494 us; speedup vs baseline: 1.0448x; 1.0448x over previous
//
#include <hip/hip_runtime.h>
#include <math.h>

// Problem geometry (fixed by the reference): B=32, C=16, H=W=256.
#define HW 65536
#define HW4 16384          // float4 groups per channel-plane
#define CTOT 16
#define BATCH 32
#define NPIX (BATCH * HW)  // 2,097,152 pixels per channel
#define NGRP (NPIX / 4)    // 524,288 float4 groups per channel

// Proven best (R7): 2048 task-specialized blocks sweeping contiguous spans,
// ALL global reads NON-TEMPORAL (no L3 allocate on miss -> no forced
// eviction/writeback of the harness poison-fill's dirty Infinity-Cache
// lines during our window; this was the 107 -> <77 us win).
// R8: fused finalize w/ __threadfence REGRESSED 2x (buffer_wbl2 x 2048).
// R9: memset-free per-block slots, but runtime-indexed finalize -> scratch
//     serial RMWs, +30us (rule #20).
// R10: static-indexed finalize (width-16 segmented shuffle) -> 263.1 us. BEST.
// R11: atomics-based fused finalize -> 268.0 (+4.9): last-arriver can't start
//     earlier than a separate dispatch anyway; publication atomics on every
//     block's critical path cost more than the saved launch gap. REVERTED.
// R12 (this round): R10 structure exactly; one tweak: len/angle unroll 2->4
//     (8->16 loads in flight, matching the displacement branch's MLP; no
//     VGPR-watermark increase since disp branch already holds 16 float4).
#define GRID_BLOCKS 2048

typedef float f32x4 __attribute__((ext_vector_type(4)));

__device__ __forceinline__ float4 ldnt(const float4* p) {
    f32x4 v = __builtin_nontemporal_load((const f32x4*)p);
    float4 r; r.x = v.x; r.y = v.y; r.z = v.z; r.w = v.w;
    return r;
}

__device__ __forceinline__ float smooth_l1(float p, float g) {
    float d = fabsf(p - g);
    return (d < 1.0f) ? 0.5f * d * d : d - 0.5f;
}
// a=|x| >= 0 so 1+exp(-a) in (1,2]: plain __logf is safe (abs err < 6e-8).
__device__ __forceinline__ float bce_logits(float x, float t) {
    float e = __expf(-fabsf(x));
    return fmaxf(x, 0.0f) - x * t + __logf(1.0f + e);
}
__device__ __forceinline__ float sigmoid_fast(float x) {
    return __builtin_amdgcn_rcpf(1.0f + __expf(-x));
}
__device__ __forceinline__ float get4(const float4& v, int j) {
    return j == 0 ? v.x : (j == 1 ? v.y : (j == 2 ? v.z : v.w));
}

__global__ __launch_bounds__(256) void loss_kernel(const float* __restrict__ preds,
                                                   const float* __restrict__ gts,
                                                   float4* __restrict__ ws) {
    const float4* pf = (const float4*)preds;
    const float4* gf = (const float4*)gts;
    const int blk = blockIdx.x;
    const int tid = threadIdx.x;

    float acc0 = 0.0f, acc1 = 0.0f, acc2 = 0.0f;

    if (blk < 512) {
        // ---------------- BCE task: 2 dense streams ----------------
        const int task = blk >> 7;                    // 0..3
        const int chs[4]   = {15, 14, 0, 7};
        const int ch = chs[task];
        const int lblk = blk & 127;
        const int start = lblk << 12;                 // span 4096 groups
        const int b = start >> 14;
        const int hw4s = start & (HW4 - 1);
        const size_t off = ((size_t)b * CTOT + ch) * HW4 + hw4s;
        const float4* pp = pf + off;
        const float4* gp = gf + off;
#pragma unroll 4
        for (int i = 0; i < 16; ++i) {
            const int o = (i << 8) + tid;
            float4 p = ldnt(pp + o);
            float4 t = ldnt(gp + o);
#pragma unroll
            for (int j = 0; j < 4; ++j) {
                float x  = get4(p, j);
                float tv = get4(t, j);
                float loss = bce_logits(x, tv);
                float pos  = (tv != 0.0f) ? 1.0f : 0.0f;
                acc0 += loss * pos;
                acc1 += loss * (1.0f - pos);
                acc2 += pos;
            }
        }
    } else if (blk < 1536) {
        // ---------------- displacement task: 8 dense streams ----------------
        const int task = (blk - 512) >> 9;            // 0..1
        const int c0 = task == 0 ? 1 : 8;
        const int lblk = (blk - 512) & 511;
        const int start = lblk << 10;                 // span 1024 groups
        const int b = start >> 14;
        const int hw4s = start & (HW4 - 1);
        const size_t off = ((size_t)b * CTOT + c0) * HW4 + hw4s;
        const float4* pp = pf + off;
        const float4* gp = gf + off;
#pragma unroll 2
        for (int i = 0; i < 4; ++i) {
            const int o = (i << 8) + tid;
            float4 p0 = ldnt(pp + o + 0 * HW4);
            float4 p1 = ldnt(pp + o + 1 * HW4);
            float4 p2 = ldnt(pp + o + 2 * HW4);
            float4 p3 = ldnt(pp + o + 3 * HW4);
            float4 g0 = ldnt(gp + o + 0 * HW4);
            float4 g1 = ldnt(gp + o + 1 * HW4);
            float4 g2 = ldnt(gp + o + 2 * HW4);
            float4 g3 = ldnt(gp + o + 3 * HW4);
#pragma unroll
            for (int j = 0; j < 4; ++j) {
                float a0 = get4(p0, j), a1 = get4(p1, j), a2 = get4(p2, j), a3 = get4(p3, j);
                float b0 = get4(g0, j), b1 = get4(g1, j), b2 = get4(g2, j), b3 = get4(g3, j);
                float posv = fabsf(b0) + fabsf(b1) + fabsf(b2) + fabsf(b3);
                float m = (posv != 0.0f) ? 1.0f : 0.0f;
                float l1 = smooth_l1(a0, b0) + smooth_l1(a1, b1) +
                           smooth_l1(a2, b2) + smooth_l1(a3, b3);
                // swap = concat(pred[2:], pred[:2]) -> [p2,p3,p0,p1] vs gt
                float l2 = smooth_l1(a2, b0) + smooth_l1(a3, b1) +
                           smooth_l1(a0, b2) + smooth_l1(a1, b3);
                acc0 += fminf(l1, l2) * m;
                acc1 += m;
            }
        }
    } else {
        // ---------------- len/angle task: 4 dense streams ----------------
        const int task = (blk - 1536) >> 8;           // 0..1
        const int cl = task == 0 ? 5 : 12;
        const int lblk = (blk - 1536) & 255;
        const int start = lblk << 11;                 // span 2048 groups
        const int b = start >> 14;
        const int hw4s = start & (HW4 - 1);
        const size_t off = ((size_t)b * CTOT + cl) * HW4 + hw4s;
        const float4* pp = pf + off;
        const float4* gp = gf + off;
#pragma unroll 4
        for (int i = 0; i < 8; ++i) {
            const int o = (i << 8) + tid;
            float4 pl = ldnt(pp + o + 0 * HW4);
            float4 pa = ldnt(pp + o + 1 * HW4);
            float4 gl = ldnt(gp + o + 0 * HW4);
            float4 ga = ldnt(gp + o + 1 * HW4);
#pragma unroll
            for (int j = 0; j < 4; ++j) {
                float glv = get4(gl, j);
                float m = (glv != 0.0f) ? 1.0f : 0.0f;
                acc0 += smooth_l1(sigmoid_fast(get4(pl, j)), glv) * m;
                acc1 += smooth_l1(sigmoid_fast(get4(pa, j)), get4(ga, j)) * m;
                acc2 += m;
            }
        }
    }

    // ---- wave (64-lane) butterfly reduce the (up to) 3 accumulators ----
#pragma unroll
    for (int off = 32; off > 0; off >>= 1) {
        acc0 += __shfl_down(acc0, off, 64);
        acc1 += __shfl_down(acc1, off, 64);
        acc2 += __shfl_down(acc2, off, 64);
    }

    __shared__ float red[4][3];
    const int lane = threadIdx.x & 63;
    const int wid  = threadIdx.x >> 6;
    if (lane == 0) { red[wid][0] = acc0; red[wid][1] = acc1; red[wid][2] = acc2; }
    __syncthreads();
    if (threadIdx.x == 0) {
        float4 v;
        v.x = red[0][0] + red[1][0] + red[2][0] + red[3][0];
        v.y = red[0][1] + red[1][1] + red[2][1] + red[3][1];
        v.z = red[0][2] + red[1][2] + red[2][2] + red[3][2];
        v.w = 0.0f;
        // Dedicated slot per block: no zero-init needed, no atomics.
        ws[blk] = v;
    }
}

// Reduces the 2048 per-block float4 partials and emits the final scalar.
// Thread t owns slots [8t, 8t+8). Every task-region boundary (128, 256,
// 384, 512, 1024, 1536, 1792 blocks) is a multiple of 128 blocks = 16
// threads, so each width-16 shuffle segment maps to exactly ONE region
// slice:
//   seg  0: blocks    0- 127  line_seg   (BCE ch15)
//   seg  1: blocks  128- 255  junc_seg   (BCE ch14)
//   seg  2: blocks  256- 383  sol_center (BCE ch0)
//   seg  3: blocks  384- 511  tp_center  (BCE ch7)
//   seg 4-7: blocks 512-1023  sol_disp
//   seg 8-11: blocks 1024-1535 tp_disp
//   seg 12-13: blocks 1536-1791 sol len/angle
//   seg 14-15: blocks 1792-2047 tp len/angle
// Thread 0 combines the 16 LDS entries with COMPILE-TIME indices only
// (no runtime-indexed array -> no scratch; that was R9's +30us bug).
__global__ __launch_bounds__(256) void finalize_kernel(const float4* __restrict__ ws,
                                                       float* __restrict__ out) {
    const int tid = threadIdx.x;
    const int blk0 = tid << 3;

    double s0 = 0.0, s1 = 0.0, s2 = 0.0;
#pragma unroll
    for (int k = 0; k < 8; ++k) {
        float4 v = ws[blk0 + k];
        s0 += (double)v.x; s1 += (double)v.y; s2 += (double)v.z;
    }

    // width-16 segmented butterfly reduce
#pragma unroll
    for (int off = 8; off > 0; off >>= 1) {
        s0 += __shfl_down(s0, off, 16);
        s1 += __shfl_down(s1, off, 16);
        s2 += __shfl_down(s2, off, 16);
    }

    __shared__ double sm0[16], sm1[16], sm2[16];
    if ((tid & 15) == 0) {
        const int k = tid >> 4;
        sm0[k] = s0; sm1[k] = s1; sm2[k] = s2;
    }
    __syncthreads();

    if (tid == 0) {
        const double N = (double)NPIX;
        double line_seg   = sm0[0] / sm2[0] +  1.0 * (sm1[0] / (N - sm2[0]));
        double junc_seg   = sm0[1] / sm2[1] + 30.0 * (sm1[1] / (N - sm2[1]));
        double sol_center = sm0[2] / sm2[2] + 30.0 * (sm1[2] / (N - sm2[2]));
        double tp_center  = sm0[3] / sm2[3] + 30.0 * (sm1[3] / (N - sm2[3]));

        double sol_disp = (sm0[4] + sm0[5] + sm0[6] + sm0[7]) /
                          (sm1[4] + sm1[5] + sm1[6] + sm1[7]);
        double tp_disp  = (sm0[8] + sm0[9] + sm0[10] + sm0[11]) /
                          (sm1[8] + sm1[9] + sm1[10] + sm1[11]);

        double sl_d = sm2[12] + sm2[13];
        double sol_len   = (sm0[12] + sm0[13]) / sl_d;
        double sol_angle = (sm1[12] + sm1[13]) / sl_d;
        double tl_d = sm2[14] + sm2[15];
        double tp_len    = (sm0[14] + sm0[15]) / tl_d;
        double tp_angle  = (sm1[14] + sm1[15]) / tl_d;

        double total = 10.0 * tp_center + tp_disp + tp_len + tp_angle +
                       sol_center + sol_disp + sol_len + sol_angle +
                       line_seg + junc_seg;
        out[0] = (float)total;
    }
}

extern "C" void kernel_launch(void* const* d_in, const int* in_sizes, int n_in,
                              void* d_out, int out_size, void* d_ws, size_t ws_size,
                              hipStream_t stream) {
    const float* preds = (const float*)d_in[0];
    const float* gts   = (const float*)d_in[1];
    float4* ws = (float4*)d_ws;

    loss_kernel<<<GRID_BLOCKS, 256, 0, stream>>>(preds, gts, ws);
    finalize_kernel<<<1, 256, 0, stream>>>(ws, (float*)d_out);
}